// Round 7
// baseline (166.869 us; speedup 1.0000x reference)
//
#include <hip/hip_runtime.h>

#define BATCH 2
#define NTOK 256
#define DM 512
#define NH 8
#define HDIM 64
#define PD 520   // padded bf16 row stride (elements)

typedef unsigned int uint32;
typedef unsigned short ushort16;

static __device__ __forceinline__ ushort16 bf16_rne(float x) {
  uint32 u = __float_as_uint(x);
  u += 0x7fffu + ((u >> 16) & 1u);
  return (ushort16)(u >> 16);
}
static __device__ __forceinline__ float bf16_lo(uint32 u) {
  return __uint_as_float(u << 16);
}
static __device__ __forceinline__ float bf16_hi(uint32 u) {
  return __uint_as_float(u & 0xffff0000u);
}

// ---------------- prep: per-token projections + Taylor-moment tables ----------------
// One block per token q (=b*NTOK+tok), 512 thr (t=d).
// Sv fp32 [q][d];  Pb,Pv,Pv2 bf16 [q][PD];  SbW bf16 [b][h][tok][PD] = -0.5*W2[d,h]*sb;
// Dj fp32 [q][8] = sum_d W2[d,h]*(-0.5*pb + 0.25*pb^2)   (key-side softmax bias)
__global__ __launch_bounds__(512) void prep_pe(
    const float* __restrict__ coords,
    const float* __restrict__ Wb1, const float* __restrict__ bb1,
    const float* __restrict__ Wv1, const float* __restrict__ bv1,
    const float* __restrict__ Wb2,
    float* __restrict__ Sv, ushort16* __restrict__ SbW,
    ushort16* __restrict__ Pb, ushort16* __restrict__ Pv,
    ushort16* __restrict__ Pv2, float* __restrict__ Dj) {
  __shared__ float redD[8][8];
  int q = blockIdx.x;          // b*NTOK + tok
  int b = q >> 8;
  int tok = q & (NTOK - 1);
  int d = threadIdx.x;
  const float* cp = coords + q * 3;
  float c0 = cp[0], c1 = cp[1], c2 = cp[2];
  float pb = Wb1[d * 3 + 0] * c0 + Wb1[d * 3 + 1] * c1 + Wb1[d * 3 + 2] * c2;
  float pv = Wv1[d * 3 + 0] * c0 + Wv1[d * 3 + 1] * c1 + Wv1[d * 3 + 2] * c2;
  float sb = pb + bb1[d];
  float sv = pv + bv1[d];
  Sv[(size_t)q * DM + d] = sv;
  Pb [(size_t)q * PD + d] = bf16_rne(pb);
  Pv [(size_t)q * PD + d] = bf16_rne(pv);
  Pv2[(size_t)q * PD + d] = bf16_rne(pv * pv);
  float w2[NH];
#pragma unroll
  for (int h = 0; h < NH; ++h) w2[h] = Wb2[h * DM + d];
#pragma unroll
  for (int h = 0; h < NH; ++h)
    SbW[((size_t)(b * NH + h) * NTOK + tok) * PD + d] = bf16_rne(-0.5f * w2[h] * sb);
  // D reduction
  float u = -0.5f * pb + 0.25f * pb * pb;
  float dp[NH];
#pragma unroll
  for (int h = 0; h < NH; ++h) dp[h] = w2[h] * u;
#pragma unroll
  for (int off = 32; off >= 1; off >>= 1) {
#pragma unroll
    for (int h = 0; h < NH; ++h) dp[h] += __shfl_xor(dp[h], off);
  }
  int lane = d & 63, wid = d >> 6;
  if (lane == 0) {
#pragma unroll
    for (int h = 0; h < NH; ++h) redD[wid][h] = dp[h];
  }
  __syncthreads();
  if (d < NH) {
    float s = 0.f;
#pragma unroll
    for (int w = 0; w < 8; ++w) s += redD[w][d];
    Dj[(size_t)q * NH + d] = s;
  }
}

// ---------------- QKV projection GEMM (0.125 scale folded into Q) ----------------
__global__ __launch_bounds__(256) void qkv_gemm(
    const float* __restrict__ X, const float* __restrict__ W,
    const float* __restrict__ bqkv,
    float* __restrict__ Q, float* __restrict__ K, float* __restrict__ V) {
  __shared__ float Xs[64][33];
  __shared__ float Ws[64][33];
  int t = threadIdx.x;
  int bm = blockIdx.x, bn = blockIdx.y;
  int lrow = t >> 2, lk = (t & 3) * 8;
  const float* Xp = X + (bm * 64 + lrow) * DM + lk;
  const float* Wp = W + (bn * 64 + lrow) * DM + lk;
  int tx = t & 15, ty = t >> 4;
  float acc[4][4] = {};
  for (int k0 = 0; k0 < DM; k0 += 32) {
    float4 xa = *(const float4*)(Xp + k0);
    float4 xb = *(const float4*)(Xp + k0 + 4);
    float4 wa = *(const float4*)(Wp + k0);
    float4 wb = *(const float4*)(Wp + k0 + 4);
    __syncthreads();
    Xs[lrow][lk + 0] = xa.x; Xs[lrow][lk + 1] = xa.y;
    Xs[lrow][lk + 2] = xa.z; Xs[lrow][lk + 3] = xa.w;
    Xs[lrow][lk + 4] = xb.x; Xs[lrow][lk + 5] = xb.y;
    Xs[lrow][lk + 6] = xb.z; Xs[lrow][lk + 7] = xb.w;
    Ws[lrow][lk + 0] = wa.x; Ws[lrow][lk + 1] = wa.y;
    Ws[lrow][lk + 2] = wa.z; Ws[lrow][lk + 3] = wa.w;
    Ws[lrow][lk + 4] = wb.x; Ws[lrow][lk + 5] = wb.y;
    Ws[lrow][lk + 6] = wb.z; Ws[lrow][lk + 7] = wb.w;
    __syncthreads();
#pragma unroll
    for (int kk = 0; kk < 32; ++kk) {
      float a0 = Xs[ty * 4 + 0][kk], a1 = Xs[ty * 4 + 1][kk];
      float a2 = Xs[ty * 4 + 2][kk], a3 = Xs[ty * 4 + 3][kk];
      float b0 = Ws[tx * 4 + 0][kk], b1 = Ws[tx * 4 + 1][kk];
      float b2 = Ws[tx * 4 + 2][kk], b3 = Ws[tx * 4 + 3][kk];
      acc[0][0] = fmaf(a0, b0, acc[0][0]); acc[0][1] = fmaf(a0, b1, acc[0][1]);
      acc[0][2] = fmaf(a0, b2, acc[0][2]); acc[0][3] = fmaf(a0, b3, acc[0][3]);
      acc[1][0] = fmaf(a1, b0, acc[1][0]); acc[1][1] = fmaf(a1, b1, acc[1][1]);
      acc[1][2] = fmaf(a1, b2, acc[1][2]); acc[1][3] = fmaf(a1, b3, acc[1][3]);
      acc[2][0] = fmaf(a2, b0, acc[2][0]); acc[2][1] = fmaf(a2, b1, acc[2][1]);
      acc[2][2] = fmaf(a2, b2, acc[2][2]); acc[2][3] = fmaf(a2, b3, acc[2][3]);
      acc[3][0] = fmaf(a3, b0, acc[3][0]); acc[3][1] = fmaf(a3, b1, acc[3][1]);
      acc[3][2] = fmaf(a3, b2, acc[3][2]); acc[3][3] = fmaf(a3, b3, acc[3][3]);
    }
  }
#pragma unroll
  for (int r = 0; r < 4; ++r) {
    int row = bm * 64 + ty * 4 + r;
    int b = row >> 8, i = row & (NTOK - 1);
#pragma unroll
    for (int c = 0; c < 4; ++c) {
      int n = bn * 64 + tx * 4 + c;
      float val = acc[r][c] + bqkv[n];
      if (n < DM) {
        Q[(b * NTOK + i) * DM + n] = val * 0.125f;   // qk scale folded
      } else if (n < 2 * DM) {
        int u = n - DM; int h = u >> 6, dp = u & 63;
        K[((b * NH + h) * NTOK + i) * HDIM + dp] = val;
      } else {
        int u = n - 2 * DM; int h = u >> 6, dp = u & 63;
        V[((b * NH + h) * NTOK + i) * HDIM + dp] = val;
      }
    }
  }
}

// ---------------- qkC_gemm: S[bh][i][j] = 0.125*qk - 0.5*C  (K = 64 fp32 + 512 bf16) ----
__global__ __launch_bounds__(256) void qkC_gemm(
    const float* __restrict__ Q, const float* __restrict__ K,
    const ushort16* __restrict__ SbW, const ushort16* __restrict__ Pb,
    float* __restrict__ S) {
  __shared__ float As[64][33];
  __shared__ float Bs[64][33];
  int t = threadIdx.x;
  int bh = blockIdx.y;
  int b = bh >> 3, h = bh & 7;
  int i0 = (blockIdx.x >> 2) * 64;
  int j0 = (blockIdx.x & 3) * 64;
  int lrow = t >> 2, lk = (t & 3) * 8;
  int tx = t & 15, ty = t >> 4;
  float acc[4][4] = {};

  // phase 1: qk over K=64 (fp32, scale pre-folded into Q)
  {
    const float* Qp = Q + (size_t)(b * NTOK + i0 + lrow) * DM + h * HDIM + lk;
    const float* Kp = K + ((size_t)(b * NH + h) * NTOK + j0 + lrow) * HDIM + lk;
    for (int k0 = 0; k0 < HDIM; k0 += 32) {
      float4 qa = *(const float4*)(Qp + k0);
      float4 qb = *(const float4*)(Qp + k0 + 4);
      float4 ka = *(const float4*)(Kp + k0);
      float4 kb = *(const float4*)(Kp + k0 + 4);
      __syncthreads();
      As[lrow][lk + 0] = qa.x; As[lrow][lk + 1] = qa.y;
      As[lrow][lk + 2] = qa.z; As[lrow][lk + 3] = qa.w;
      As[lrow][lk + 4] = qb.x; As[lrow][lk + 5] = qb.y;
      As[lrow][lk + 6] = qb.z; As[lrow][lk + 7] = qb.w;
      Bs[lrow][lk + 0] = ka.x; Bs[lrow][lk + 1] = ka.y;
      Bs[lrow][lk + 2] = ka.z; Bs[lrow][lk + 3] = ka.w;
      Bs[lrow][lk + 4] = kb.x; Bs[lrow][lk + 5] = kb.y;
      Bs[lrow][lk + 6] = kb.z; Bs[lrow][lk + 7] = kb.w;
      __syncthreads();
#pragma unroll
      for (int kk = 0; kk < 32; ++kk) {
        float a0 = As[ty * 4 + 0][kk], a1 = As[ty * 4 + 1][kk];
        float a2 = As[ty * 4 + 2][kk], a3 = As[ty * 4 + 3][kk];
        float b0 = Bs[tx * 4 + 0][kk], b1 = Bs[tx * 4 + 1][kk];
        float b2 = Bs[tx * 4 + 2][kk], b3 = Bs[tx * 4 + 3][kk];
        acc[0][0] = fmaf(a0, b0, acc[0][0]); acc[0][1] = fmaf(a0, b1, acc[0][1]);
        acc[0][2] = fmaf(a0, b2, acc[0][2]); acc[0][3] = fmaf(a0, b3, acc[0][3]);
        acc[1][0] = fmaf(a1, b0, acc[1][0]); acc[1][1] = fmaf(a1, b1, acc[1][1]);
        acc[1][2] = fmaf(a1, b2, acc[1][2]); acc[1][3] = fmaf(a1, b3, acc[1][3]);
        acc[2][0] = fmaf(a2, b0, acc[2][0]); acc[2][1] = fmaf(a2, b1, acc[2][1]);
        acc[2][2] = fmaf(a2, b2, acc[2][2]); acc[2][3] = fmaf(a2, b3, acc[2][3]);
        acc[3][0] = fmaf(a3, b0, acc[3][0]); acc[3][1] = fmaf(a3, b1, acc[3][1]);
        acc[3][2] = fmaf(a3, b2, acc[3][2]); acc[3][3] = fmaf(a3, b3, acc[3][3]);
      }
    }
  }

  // phase 2: -0.5*C over K=512 (bf16 inputs, -0.5 folded into SbW)
  {
    const ushort16* Ap = SbW + ((size_t)(bh * NTOK) + i0 + lrow) * PD + lk;
    const ushort16* Bp = Pb + ((size_t)(b * NTOK) + j0 + lrow) * PD + lk;
    for (int k0 = 0; k0 < DM; k0 += 32) {
      uint4 ga = *(const uint4*)(Ap + k0);
      uint4 gb = *(const uint4*)(Bp + k0);
      __syncthreads();
      As[lrow][lk + 0] = bf16_lo(ga.x); As[lrow][lk + 1] = bf16_hi(ga.x);
      As[lrow][lk + 2] = bf16_lo(ga.y); As[lrow][lk + 3] = bf16_hi(ga.y);
      As[lrow][lk + 4] = bf16_lo(ga.z); As[lrow][lk + 5] = bf16_hi(ga.z);
      As[lrow][lk + 6] = bf16_lo(ga.w); As[lrow][lk + 7] = bf16_hi(ga.w);
      Bs[lrow][lk + 0] = bf16_lo(gb.x); Bs[lrow][lk + 1] = bf16_hi(gb.x);
      Bs[lrow][lk + 2] = bf16_lo(gb.y); Bs[lrow][lk + 3] = bf16_hi(gb.y);
      Bs[lrow][lk + 4] = bf16_lo(gb.z); Bs[lrow][lk + 5] = bf16_hi(gb.z);
      Bs[lrow][lk + 6] = bf16_lo(gb.w); Bs[lrow][lk + 7] = bf16_hi(gb.w);
      __syncthreads();
#pragma unroll
      for (int kk = 0; kk < 32; ++kk) {
        float a0 = As[ty * 4 + 0][kk], a1 = As[ty * 4 + 1][kk];
        float a2 = As[ty * 4 + 2][kk], a3 = As[ty * 4 + 3][kk];
        float b0 = Bs[tx * 4 + 0][kk], b1 = Bs[tx * 4 + 1][kk];
        float b2 = Bs[tx * 4 + 2][kk], b3 = Bs[tx * 4 + 3][kk];
        acc[0][0] = fmaf(a0, b0, acc[0][0]); acc[0][1] = fmaf(a0, b1, acc[0][1]);
        acc[0][2] = fmaf(a0, b2, acc[0][2]); acc[0][3] = fmaf(a0, b3, acc[0][3]);
        acc[1][0] = fmaf(a1, b0, acc[1][0]); acc[1][1] = fmaf(a1, b1, acc[1][1]);
        acc[1][2] = fmaf(a1, b2, acc[1][2]); acc[1][3] = fmaf(a1, b3, acc[1][3]);
        acc[2][0] = fmaf(a2, b0, acc[2][0]); acc[2][1] = fmaf(a2, b1, acc[2][1]);
        acc[2][2] = fmaf(a2, b2, acc[2][2]); acc[2][3] = fmaf(a2, b3, acc[2][3]);
        acc[3][0] = fmaf(a3, b0, acc[3][0]); acc[3][1] = fmaf(a3, b1, acc[3][1]);
        acc[3][2] = fmaf(a3, b2, acc[3][2]); acc[3][3] = fmaf(a3, b3, acc[3][3]);
      }
    }
  }

#pragma unroll
  for (int r = 0; r < 4; ++r) {
    float4 res;
    res.x = acc[r][0]; res.y = acc[r][1]; res.z = acc[r][2]; res.w = acc[r][3];
    *(float4*)&S[((size_t)bh * NTOK + i0 + ty * 4 + r) * NTOK + j0 + tx * 4] = res;
  }
}

// ---------------- attn_softmax: score = S + D_j, softmax over j ----------------
__global__ __launch_bounds__(256) void attn_softmax(
    const float* __restrict__ S, const float* __restrict__ Dj,
    float* __restrict__ Wsm) {
  __shared__ float redm[NH][4];
  __shared__ float reds[NH][4];
  int t = threadIdx.x;
  int q = ((blockIdx.x & 7) << 6) + (blockIdx.x >> 3);   // XCD swizzle
  int b = q >> 8, qi = q & (NTOK - 1);
  int j = t;
  int lane = t & 63, w4 = t >> 6;
  const float* srow = S + ((size_t)(b * NH) * NTOK + qi) * NTOK + j;
  float4 d0 = *(const float4*)(Dj + ((size_t)(b * NTOK) + j) * NH);
  float4 d1 = *(const float4*)(Dj + ((size_t)(b * NTOK) + j) * NH + 4);
  float sc[NH];
#pragma unroll
  for (int h = 0; h < NH; ++h) sc[h] = srow[(size_t)h * NTOK * NTOK];
  sc[0] += d0.x; sc[1] += d0.y; sc[2] += d0.z; sc[3] += d0.w;
  sc[4] += d1.x; sc[5] += d1.y; sc[6] += d1.z; sc[7] += d1.w;
#pragma unroll
  for (int h = 0; h < NH; ++h) {
    float m = sc[h];
#pragma unroll
    for (int off = 32; off >= 1; off >>= 1) m = fmaxf(m, __shfl_xor(m, off));
    if (lane == 0) redm[h][w4] = m;
  }
  __syncthreads();
#pragma unroll
  for (int h = 0; h < NH; ++h) {
    float m = fmaxf(fmaxf(redm[h][0], redm[h][1]), fmaxf(redm[h][2], redm[h][3]));
    float e = __expf(sc[h] - m);
    sc[h] = e;
    float s = e;
#pragma unroll
    for (int off = 32; off >= 1; off >>= 1) s += __shfl_xor(s, off);
    if (lane == 0) reds[h][w4] = s;
  }
  __syncthreads();
#pragma unroll
  for (int h = 0; h < NH; ++h) {
    float s = (reds[h][0] + reds[h][1]) + (reds[h][2] + reds[h][3]);
    float w = sc[h] * __builtin_amdgcn_rcpf(s);
    Wsm[((size_t)(b * NH + h) * NTOK + qi) * NTOK + j] = w;
  }
}

// ---------------- pv_gemm: P1 = Wsm@Pv, P2 = Wsm@Pv2; epilogue -> g (bf16) ----------
// grid (4 i-tiles x 8 d-tiles = 32, bh = 16), 256 thr, 64i x 64d, K=256 j.
__global__ __launch_bounds__(256) void pv_gemm(
    const float* __restrict__ Wsm, const ushort16* __restrict__ Pv,
    const ushort16* __restrict__ Pv2, const float* __restrict__ Sv,
    ushort16* __restrict__ Gbf) {
  __shared__ float As[64][33];
  __shared__ float B1s[32][65];
  __shared__ float B2s[32][65];
  int t = threadIdx.x;
  int bh = blockIdx.y;
  int b = bh >> 3, h = bh & 7;
  int i0 = (blockIdx.x >> 3) * 64;
  int d0 = (blockIdx.x & 7) * 64;
  int lrow = t >> 2, lk = (t & 3) * 8;     // A: 64 rows x 32 k
  int lrV = t >> 3, lcV = (t & 7) * 8;     // B: 32 rows x 64 cols
  int tx = t & 15, ty = t >> 4;
  const float* Ap = Wsm + ((size_t)bh * NTOK + i0 + lrow) * NTOK + lk;
  const ushort16* B1p = Pv  + ((size_t)(b * NTOK) + lrV) * PD + d0 + lcV;
  const ushort16* B2p = Pv2 + ((size_t)(b * NTOK) + lrV) * PD + d0 + lcV;
  float acc1[4][4] = {};
  float acc2[4][4] = {};
  for (int k0 = 0; k0 < NTOK; k0 += 32) {
    float4 a1 = *(const float4*)(Ap + k0);
    float4 a2 = *(const float4*)(Ap + k0 + 4);
    uint4 v1 = *(const uint4*)(B1p + (size_t)k0 * PD);
    uint4 v2 = *(const uint4*)(B2p + (size_t)k0 * PD);
    __syncthreads();
    As[lrow][lk + 0] = a1.x; As[lrow][lk + 1] = a1.y;
    As[lrow][lk + 2] = a1.z; As[lrow][lk + 3] = a1.w;
    As[lrow][lk + 4] = a2.x; As[lrow][lk + 5] = a2.y;
    As[lrow][lk + 6] = a2.z; As[lrow][lk + 7] = a2.w;
    B1s[lrV][lcV + 0] = bf16_lo(v1.x); B1s[lrV][lcV + 1] = bf16_hi(v1.x);
    B1s[lrV][lcV + 2] = bf16_lo(v1.y); B1s[lrV][lcV + 3] = bf16_hi(v1.y);
    B1s[lrV][lcV + 4] = bf16_lo(v1.z); B1s[lrV][lcV + 5] = bf16_hi(v1.z);
    B1s[lrV][lcV + 6] = bf16_lo(v1.w); B1s[lrV][lcV + 7] = bf16_hi(v1.w);
    B2s[lrV][lcV + 0] = bf16_lo(v2.x); B2s[lrV][lcV + 1] = bf16_hi(v2.x);
    B2s[lrV][lcV + 2] = bf16_lo(v2.y); B2s[lrV][lcV + 3] = bf16_hi(v2.y);
    B2s[lrV][lcV + 4] = bf16_lo(v2.z); B2s[lrV][lcV + 5] = bf16_hi(v2.z);
    B2s[lrV][lcV + 6] = bf16_lo(v2.w); B2s[lrV][lcV + 7] = bf16_hi(v2.w);
    __syncthreads();
#pragma unroll
    for (int kk = 0; kk < 32; ++kk) {
      float a0 = As[ty * 4 + 0][kk], a1v = As[ty * 4 + 1][kk];
      float a2v = As[ty * 4 + 2][kk], a3v = As[ty * 4 + 3][kk];
      float4 b1 = *(const float4*)&B1s[kk][tx * 4];
      float4 b2 = *(const float4*)&B2s[kk][tx * 4];
      acc1[0][0] = fmaf(a0,  b1.x, acc1[0][0]); acc1[0][1] = fmaf(a0,  b1.y, acc1[0][1]);
      acc1[0][2] = fmaf(a0,  b1.z, acc1[0][2]); acc1[0][3] = fmaf(a0,  b1.w, acc1[0][3]);
      acc1[1][0] = fmaf(a1v, b1.x, acc1[1][0]); acc1[1][1] = fmaf(a1v, b1.y, acc1[1][1]);
      acc1[1][2] = fmaf(a1v, b1.z, acc1[1][2]); acc1[1][3] = fmaf(a1v, b1.w, acc1[1][3]);
      acc1[2][0] = fmaf(a2v, b1.x, acc1[2][0]); acc1[2][1] = fmaf(a2v, b1.y, acc1[2][1]);
      acc1[2][2] = fmaf(a2v, b1.z, acc1[2][2]); acc1[2][3] = fmaf(a2v, b1.w, acc1[2][3]);
      acc1[3][0] = fmaf(a3v, b1.x, acc1[3][0]); acc1[3][1] = fmaf(a3v, b1.y, acc1[3][1]);
      acc1[3][2] = fmaf(a3v, b1.z, acc1[3][2]); acc1[3][3] = fmaf(a3v, b1.w, acc1[3][3]);
      acc2[0][0] = fmaf(a0,  b2.x, acc2[0][0]); acc2[0][1] = fmaf(a0,  b2.y, acc2[0][1]);
      acc2[0][2] = fmaf(a0,  b2.z, acc2[0][2]); acc2[0][3] = fmaf(a0,  b2.w, acc2[0][3]);
      acc2[1][0] = fmaf(a1v, b2.x, acc2[1][0]); acc2[1][1] = fmaf(a1v, b2.y, acc2[1][1]);
      acc2[1][2] = fmaf(a1v, b2.z, acc2[1][2]); acc2[1][3] = fmaf(a1v, b2.w, acc2[1][3]);
      acc2[2][0] = fmaf(a2v, b2.x, acc2[2][0]); acc2[2][1] = fmaf(a2v, b2.y, acc2[2][1]);
      acc2[2][2] = fmaf(a2v, b2.z, acc2[2][2]); acc2[2][3] = fmaf(a2v, b2.w, acc2[2][3]);
      acc2[3][0] = fmaf(a3v, b2.x, acc2[3][0]); acc2[3][1] = fmaf(a3v, b2.y, acc2[3][1]);
      acc2[3][2] = fmaf(a3v, b2.z, acc2[3][2]); acc2[3][3] = fmaf(a3v, b2.w, acc2[3][3]);
    }
  }
  // epilogue: g = 0.5*(sv - P1) + 0.25*(sv^2 - 2*sv*P1 + P2), bf16
#pragma unroll
  for (int r = 0; r < 4; ++r) {
    int gi = b * NTOK + i0 + ty * 4 + r;
    float4 sv = *(const float4*)&Sv[(size_t)gi * DM + d0 + tx * 4];
    float g0 = 0.5f * (sv.x - acc1[r][0]) +
               0.25f * (sv.x * sv.x - 2.f * sv.x * acc1[r][0] + acc2[r][0]);
    float g1 = 0.5f * (sv.y - acc1[r][1]) +
               0.25f * (sv.y * sv.y - 2.f * sv.y * acc1[r][1] + acc2[r][1]);
    float g2 = 0.5f * (sv.z - acc1[r][2]) +
               0.25f * (sv.z * sv.z - 2.f * sv.z * acc1[r][2] + acc2[r][2]);
    float g3 = 0.5f * (sv.w - acc1[r][3]) +
               0.25f * (sv.w * sv.w - 2.f * sv.w * acc1[r][3] + acc2[r][3]);
    uint2 pk;
    pk.x = (uint32)bf16_rne(g0) | ((uint32)bf16_rne(g1) << 16);
    pk.y = (uint32)bf16_rne(g2) | ((uint32)bf16_rne(g3) << 16);
    *(uint2*)&Gbf[((size_t)gi * NH + h) * DM + d0 + tx * 4] = pk;
  }
}

// ---------------- out GEMM: out = Wsm @ V + G @ Wv2^T + bv2, per head ----------------
__global__ __launch_bounds__(256) void out_gemm(
    const ushort16* __restrict__ Gbf, const float* __restrict__ Wsm,
    const float* __restrict__ Wv2, const float* __restrict__ V,
    const float* __restrict__ bv2, float* __restrict__ out) {
  __shared__ float As[32][33];
  __shared__ float Bs[64][33];
  int t = threadIdx.x;
  int bm = blockIdx.x;       // 32-query tile
  int h = blockIdx.y;        // head
  int tx = t & 15, ty = t >> 4;
  float acc[2][4] = {};

  // GEMM1: G(32 x 512, bf16) @ Wv2_h^T(512 x 64)
  {
    int lrA = t >> 3, lkA = (t & 7) * 4;
    int lrB = t >> 2, lkB = (t & 3) * 8;
    const ushort16* Ap = Gbf + ((size_t)(bm * 32 + lrA) * NH + h) * DM + lkA;
    const float* Bp = Wv2 + (size_t)(h * 64 + lrB) * DM + lkB;
    for (int k0 = 0; k0 < DM; k0 += 32) {
      uint2 ga = *(const uint2*)(Ap + k0);
      float4 w1 = *(const float4*)(Bp + k0);
      float4 w2 = *(const float4*)(Bp + k0 + 4);
      __syncthreads();
      As[lrA][lkA + 0] = bf16_lo(ga.x); As[lrA][lkA + 1] = bf16_hi(ga.x);
      As[lrA][lkA + 2] = bf16_lo(ga.y); As[lrA][lkA + 3] = bf16_hi(ga.y);
      Bs[lrB][lkB + 0] = w1.x; Bs[lrB][lkB + 1] = w1.y;
      Bs[lrB][lkB + 2] = w1.z; Bs[lrB][lkB + 3] = w1.w;
      Bs[lrB][lkB + 4] = w2.x; Bs[lrB][lkB + 5] = w2.y;
      Bs[lrB][lkB + 6] = w2.z; Bs[lrB][lkB + 7] = w2.w;
      __syncthreads();
#pragma unroll
      for (int kk = 0; kk < 32; ++kk) {
        float a0 = As[ty * 2 + 0][kk], a1 = As[ty * 2 + 1][kk];
        float b0 = Bs[tx * 4 + 0][kk], b1 = Bs[tx * 4 + 1][kk];
        float b2 = Bs[tx * 4 + 2][kk], b3 = Bs[tx * 4 + 3][kk];
        acc[0][0] = fmaf(a0, b0, acc[0][0]); acc[0][1] = fmaf(a0, b1, acc[0][1]);
        acc[0][2] = fmaf(a0, b2, acc[0][2]); acc[0][3] = fmaf(a0, b3, acc[0][3]);
        acc[1][0] = fmaf(a1, b0, acc[1][0]); acc[1][1] = fmaf(a1, b1, acc[1][1]);
        acc[1][2] = fmaf(a1, b2, acc[1][2]); acc[1][3] = fmaf(a1, b3, acc[1][3]);
      }
    }
  }

  // GEMM2: Wsm(32 x 256) @ V(256 x 64)
  {
    int lrA = t >> 3, lkA = (t & 7) * 4;
    int lrV = t >> 3, lcV = (t & 7) * 8;
    int b = bm >> 3;
    int row = bm * 32 + lrA;
    const float* A2p = Wsm + ((size_t)(b * NH + h) * NTOK + (row & (NTOK - 1))) * NTOK + lkA;
    const float* Vp = V + ((size_t)(b * NH + h) * NTOK + lrV) * HDIM + lcV;
    float (*Vs)[65] = (float(*)[65])&Bs[0][0];
    for (int k0 = 0; k0 < NTOK; k0 += 32) {
      float4 a4 = *(const float4*)(A2p + k0);
      float4 v1 = *(const float4*)(Vp + (size_t)k0 * HDIM);
      float4 v2 = *(const float4*)(Vp + (size_t)k0 * HDIM + 4);
      __syncthreads();
      As[lrA][lkA + 0] = a4.x; As[lrA][lkA + 1] = a4.y;
      As[lrA][lkA + 2] = a4.z; As[lrA][lkA + 3] = a4.w;
      Vs[lrV][lcV + 0] = v1.x; Vs[lrV][lcV + 1] = v1.y;
      Vs[lrV][lcV + 2] = v1.z; Vs[lrV][lcV + 3] = v1.w;
      Vs[lrV][lcV + 4] = v2.x; Vs[lrV][lcV + 5] = v2.y;
      Vs[lrV][lcV + 6] = v2.z; Vs[lrV][lcV + 7] = v2.w;
      __syncthreads();
#pragma unroll
      for (int kk = 0; kk < 32; ++kk) {
        float a0 = As[ty * 2 + 0][kk], a1 = As[ty * 2 + 1][kk];
        float b0 = Vs[kk][tx * 4 + 0], b1 = Vs[kk][tx * 4 + 1];
        float b2 = Vs[kk][tx * 4 + 2], b3 = Vs[kk][tx * 4 + 3];
        acc[0][0] = fmaf(a0, b0, acc[0][0]); acc[0][1] = fmaf(a0, b1, acc[0][1]);
        acc[0][2] = fmaf(a0, b2, acc[0][2]); acc[0][3] = fmaf(a0, b3, acc[0][3]);
        acc[1][0] = fmaf(a1, b0, acc[1][0]); acc[1][1] = fmaf(a1, b1, acc[1][1]);
        acc[1][2] = fmaf(a1, b2, acc[1][2]); acc[1][3] = fmaf(a1, b3, acc[1][3]);
      }
    }
  }

  int o0 = h * 64 + tx * 4;
  float4 bvq = *(const float4*)(bv2 + o0);
#pragma unroll
  for (int r = 0; r < 2; ++r) {
    int bi = bm * 32 + ty * 2 + r;
    float4 res;
    res.x = acc[r][0] + bvq.x;
    res.y = acc[r][1] + bvq.y;
    res.z = acc[r][2] + bvq.z;
    res.w = acc[r][3] + bvq.w;
    *(float4*)&out[(size_t)bi * DM + o0] = res;
  }
}

extern "C" void kernel_launch(void* const* d_in, const int* in_sizes, int n_in,
                              void* d_out, int out_size, void* d_ws, size_t ws_size,
                              hipStream_t stream) {
  const float* x      = (const float*)d_in[0];
  const float* coords = (const float*)d_in[1];
  const float* Wqkv   = (const float*)d_in[2];
  const float* bqkv   = (const float*)d_in[3];
  const float* Wb1    = (const float*)d_in[4];
  const float* bb1    = (const float*)d_in[5];
  const float* Wb2    = (const float*)d_in[6];
  // d_in[7] = bb2: softmax-invariant, unused
  const float* Wv1    = (const float*)d_in[8];
  const float* bv1    = (const float*)d_in[9];
  const float* Wv2    = (const float*)d_in[10];
  const float* bv2    = (const float*)d_in[11];
  float* outp = (float*)d_out;
  float* ws = (float*)d_ws;

  const size_t SZ   = (size_t)BATCH * NTOK * DM;            // 262144 floats
  const size_t SQ   = (size_t)BATCH * NH * NTOK * NTOK;     // 1048576 floats
  const size_t PROW = (size_t)BATCH * NTOK * PD;            // 266240 bf16 elems
  float* Qw  = ws;                   // 0.125-scaled Q
  float* Kw  = ws + SZ;
  float* Vw  = ws + 2 * SZ;
  float* Svw = ws + 3 * SZ;
  float* Sqk = ws + 4 * SZ;          // [bh][i][j]
  float* Wsm = Sqk + SQ;             // [bh][i][j]
  float* Djw = Wsm + SQ;             // [q][8]
  ushort16* Gbf = (ushort16*)(Djw + 4096);             // [q][h][d], 2M bf16
  ushort16* SbW = Gbf + (size_t)BATCH * NTOK * NH * DM;  // [bh][tok][PD]
  ushort16* Pbw = SbW + (size_t)BATCH * NH * NTOK * PD;
  ushort16* Pvw = Pbw + PROW;
  ushort16* Pv2w = Pvw + PROW;

  hipLaunchKernelGGL(prep_pe, dim3(BATCH * NTOK), dim3(512), 0, stream,
                     coords, Wb1, bb1, Wv1, bv1, Wb2,
                     Svw, SbW, Pbw, Pvw, Pv2w, Djw);
  hipLaunchKernelGGL(qkv_gemm, dim3(8, 24), dim3(256), 0, stream,
                     x, Wqkv, bqkv, Qw, Kw, Vw);
  hipLaunchKernelGGL(qkC_gemm, dim3(16, BATCH * NH), dim3(256), 0, stream,
                     Qw, Kw, SbW, Pbw, Sqk);
  hipLaunchKernelGGL(attn_softmax, dim3(BATCH * NTOK), dim3(256), 0, stream,
                     Sqk, Djw, Wsm);
  hipLaunchKernelGGL(pv_gemm, dim3(32, BATCH * NH), dim3(256), 0, stream,
                     Wsm, Pvw, Pv2w, Svw, Gbf);
  hipLaunchKernelGGL(out_gemm, dim3(16, 8), dim3(256), 0, stream,
                     Gbf, Wsm, Wv2, Vw, bv2, outp);
}

// Round 8
// 84.768 us; speedup vs baseline: 1.9685x; 1.9685x over previous
//
#include <hip/hip_runtime.h>

#define BATCH 2
#define NTOK 256
#define DM 512
#define NH 8
#define HDIM 64
#define PD 520      // bf16 row stride for d-major (k=512) tensors, mult of 8
#define TSTR 264    // bf16 row stride for j-major (k=256) tensors, mult of 8
#define WSTR 264

typedef unsigned int uint32;
typedef unsigned short ushort16;
typedef __attribute__((ext_vector_type(8))) short bf16x8;
typedef __attribute__((ext_vector_type(4))) float f32x4;

static __device__ __forceinline__ ushort16 bf16_rne(float x) {
  uint32 u = __float_as_uint(x);
  u += 0x7fffu + ((u >> 16) & 1u);
  return (ushort16)(u >> 16);
}

// load one 16x32 bf16 MFMA fragment from row-major [16dim][k] storage:
// lane l -> row (l&15), k-offset ((l>>4)*8), one 16B load.
static __device__ __forceinline__ bf16x8 ldfrag(const ushort16* p0, int stride) {
  int l = threadIdx.x & 63;
  return *(const bf16x8*)(p0 + (size_t)(l & 15) * stride + ((l >> 4) << 3));
}

// ---------------- prep: per-token tables for the Taylor-factorized pair MLPs ----------
// block = token q (512 blocks x 512 thr, t = d).
__global__ __launch_bounds__(512) void prep_pe(
    const float* __restrict__ coords,
    const float* __restrict__ Wb1, const float* __restrict__ bb1,
    const float* __restrict__ Wv1, const float* __restrict__ bv1,
    const float* __restrict__ Wb2, const float* __restrict__ Wv2,
    float* __restrict__ Sv, ushort16* __restrict__ SbW,
    ushort16* __restrict__ Pb, ushort16* __restrict__ PvT,
    ushort16* __restrict__ Pv2T, float* __restrict__ Dj,
    ushort16* __restrict__ Wv2b) {
  __shared__ float redD[8][8];
  int q = blockIdx.x;          // b*NTOK + tok
  int b = q >> 8;
  int tok = q & (NTOK - 1);
  int d = threadIdx.x;
  const float* cp = coords + q * 3;
  float c0 = cp[0], c1 = cp[1], c2 = cp[2];
  float pb = Wb1[d * 3 + 0] * c0 + Wb1[d * 3 + 1] * c1 + Wb1[d * 3 + 2] * c2;
  float pv = Wv1[d * 3 + 0] * c0 + Wv1[d * 3 + 1] * c1 + Wv1[d * 3 + 2] * c2;
  float sb = pb + bb1[d];
  float sv = pv + bv1[d];
  Sv[(size_t)q * DM + d] = sv;
  Pb[(size_t)q * PD + d] = bf16_rne(pb);
  PvT [((size_t)(b * DM) + d) * TSTR + tok] = bf16_rne(pv);
  Pv2T[((size_t)(b * DM) + d) * TSTR + tok] = bf16_rne(pv * pv);
  Wv2b[(size_t)q * PD + d] = bf16_rne(Wv2[(size_t)q * DM + d]);  // q spans 512 = rows of Wv2
  float w2[NH];
#pragma unroll
  for (int h = 0; h < NH; ++h) w2[h] = Wb2[h * DM + d];
#pragma unroll
  for (int h = 0; h < NH; ++h)
    SbW[((size_t)(b * NH + h) * NTOK + tok) * PD + d] = bf16_rne(-0.5f * w2[h] * sb);
  float u = -0.5f * pb + 0.25f * pb * pb;
  float dp[NH];
#pragma unroll
  for (int h = 0; h < NH; ++h) dp[h] = w2[h] * u;
#pragma unroll
  for (int off = 32; off >= 1; off >>= 1) {
#pragma unroll
    for (int h = 0; h < NH; ++h) dp[h] += __shfl_xor(dp[h], off);
  }
  int lane = d & 63, wid = d >> 6;
  if (lane == 0) {
#pragma unroll
    for (int h = 0; h < NH; ++h) redD[wid][h] = dp[h];
  }
  __syncthreads();
  if (d < NH) {
    float s = 0.f;
#pragma unroll
    for (int w = 0; w < 8; ++w) s += redD[w][d];
    Dj[(size_t)q * NH + d] = s;
  }
}

// ---------------- QKV projection GEMM (fp32 compute, bf16 outputs) ----------------
__global__ __launch_bounds__(256) void qkv_gemm(
    const float* __restrict__ X, const float* __restrict__ W,
    const float* __restrict__ bqkv,
    ushort16* __restrict__ Qb, ushort16* __restrict__ Kb,
    ushort16* __restrict__ VTb) {
  __shared__ float Xs[64][33];
  __shared__ float Ws[64][33];
  int t = threadIdx.x;
  int bm = blockIdx.x, bn = blockIdx.y;
  int lrow = t >> 2, lk = (t & 3) * 8;
  const float* Xp = X + (bm * 64 + lrow) * DM + lk;
  const float* Wp = W + (bn * 64 + lrow) * DM + lk;
  int tx = t & 15, ty = t >> 4;
  float acc[4][4] = {};
  for (int k0 = 0; k0 < DM; k0 += 32) {
    float4 xa = *(const float4*)(Xp + k0);
    float4 xb = *(const float4*)(Xp + k0 + 4);
    float4 wa = *(const float4*)(Wp + k0);
    float4 wb = *(const float4*)(Wp + k0 + 4);
    __syncthreads();
    Xs[lrow][lk + 0] = xa.x; Xs[lrow][lk + 1] = xa.y;
    Xs[lrow][lk + 2] = xa.z; Xs[lrow][lk + 3] = xa.w;
    Xs[lrow][lk + 4] = xb.x; Xs[lrow][lk + 5] = xb.y;
    Xs[lrow][lk + 6] = xb.z; Xs[lrow][lk + 7] = xb.w;
    Ws[lrow][lk + 0] = wa.x; Ws[lrow][lk + 1] = wa.y;
    Ws[lrow][lk + 2] = wa.z; Ws[lrow][lk + 3] = wa.w;
    Ws[lrow][lk + 4] = wb.x; Ws[lrow][lk + 5] = wb.y;
    Ws[lrow][lk + 6] = wb.z; Ws[lrow][lk + 7] = wb.w;
    __syncthreads();
#pragma unroll
    for (int kk = 0; kk < 32; ++kk) {
      float a0 = Xs[ty * 4 + 0][kk], a1 = Xs[ty * 4 + 1][kk];
      float a2 = Xs[ty * 4 + 2][kk], a3 = Xs[ty * 4 + 3][kk];
      float b0 = Ws[tx * 4 + 0][kk], b1 = Ws[tx * 4 + 1][kk];
      float b2 = Ws[tx * 4 + 2][kk], b3 = Ws[tx * 4 + 3][kk];
      acc[0][0] = fmaf(a0, b0, acc[0][0]); acc[0][1] = fmaf(a0, b1, acc[0][1]);
      acc[0][2] = fmaf(a0, b2, acc[0][2]); acc[0][3] = fmaf(a0, b3, acc[0][3]);
      acc[1][0] = fmaf(a1, b0, acc[1][0]); acc[1][1] = fmaf(a1, b1, acc[1][1]);
      acc[1][2] = fmaf(a1, b2, acc[1][2]); acc[1][3] = fmaf(a1, b3, acc[1][3]);
      acc[2][0] = fmaf(a2, b0, acc[2][0]); acc[2][1] = fmaf(a2, b1, acc[2][1]);
      acc[2][2] = fmaf(a2, b2, acc[2][2]); acc[2][3] = fmaf(a2, b3, acc[2][3]);
      acc[3][0] = fmaf(a3, b0, acc[3][0]); acc[3][1] = fmaf(a3, b1, acc[3][1]);
      acc[3][2] = fmaf(a3, b2, acc[3][2]); acc[3][3] = fmaf(a3, b3, acc[3][3]);
    }
  }
#pragma unroll
  for (int r = 0; r < 4; ++r) {
    int row = bm * 64 + ty * 4 + r;
    int b = row >> 8, i = row & (NTOK - 1);
#pragma unroll
    for (int c = 0; c < 4; ++c) {
      int n = bn * 64 + tx * 4 + c;
      float val = acc[r][c] + bqkv[n];
      if (n < DM) {
        int h = n >> 6, dp = n & 63;
        Qb[((size_t)(b * NH + h) * NTOK + i) * HDIM + dp] = bf16_rne(val * 0.125f);
      } else if (n < 2 * DM) {
        int u = n - DM; int h = u >> 6, dp = u & 63;
        Kb[((size_t)(b * NH + h) * NTOK + i) * HDIM + dp] = bf16_rne(val);
      } else {
        int u = n - 2 * DM; int h = u >> 6, dp = u & 63;
        VTb[((size_t)(b * NH + h) * HDIM + dp) * TSTR + i] = bf16_rne(val);
      }
    }
  }
}

// ---------------- score_gemm (MFMA): S = 0.125*Q·K^T - 0.5*SbW·Pb^T ----------------
// grid (16 = 4 i-tiles x 4 j-tiles, 16 bh), 256 thr = 4 waves, wave = 16i x 64j.
__global__ __launch_bounds__(256) void score_gemm(
    const ushort16* __restrict__ Qb, const ushort16* __restrict__ Kb,
    const ushort16* __restrict__ SbW, const ushort16* __restrict__ Pb,
    float* __restrict__ S) {
  int t = threadIdx.x;
  int w = t >> 6, lane = t & 63;
  int bh = blockIdx.y;
  int b = bh >> 3;
  int ib = (blockIdx.x >> 2) * 64 + w * 16;
  int j0 = (blockIdx.x & 3) * 64;
  f32x4 acc[4] = {};
  {  // qk over K=64
    const ushort16* qbase = Qb + ((size_t)bh * NTOK + ib) * HDIM;
    const ushort16* kbase = Kb + ((size_t)bh * NTOK + j0) * HDIM;
#pragma unroll
    for (int kb = 0; kb < 2; ++kb) {
      bf16x8 af = ldfrag(qbase + kb * 32, HDIM);
#pragma unroll
      for (int jj = 0; jj < 4; ++jj) {
        bf16x8 bf = ldfrag(kbase + (size_t)jj * 16 * HDIM + kb * 32, HDIM);
        acc[jj] = __builtin_amdgcn_mfma_f32_16x16x32_bf16(af, bf, acc[jj], 0, 0, 0);
      }
    }
  }
  {  // C-term over K=512 (-0.5 folded into SbW)
    const ushort16* abase = SbW + ((size_t)bh * NTOK + ib) * PD;
    const ushort16* bbase = Pb + ((size_t)(b * NTOK) + j0) * PD;
#pragma unroll 4
    for (int kb = 0; kb < 16; ++kb) {
      bf16x8 af = ldfrag(abase + kb * 32, PD);
#pragma unroll
      for (int jj = 0; jj < 4; ++jj) {
        bf16x8 bf = ldfrag(bbase + (size_t)jj * 16 * PD + kb * 32, PD);
        acc[jj] = __builtin_amdgcn_mfma_f32_16x16x32_bf16(af, bf, acc[jj], 0, 0, 0);
      }
    }
  }
  int col = lane & 15, rb = (lane >> 4) * 4;
#pragma unroll
  for (int jj = 0; jj < 4; ++jj)
#pragma unroll
    for (int r = 0; r < 4; ++r)
      S[((size_t)bh * NTOK + ib + rb + r) * NTOK + j0 + jj * 16 + col] = acc[jj][r];
}

// ---------------- attn_softmax: score = S + D_j, softmax over j -> bf16 weights ------
__global__ __launch_bounds__(256) void attn_softmax(
    const float* __restrict__ S, const float* __restrict__ Dj,
    ushort16* __restrict__ Wsmb) {
  __shared__ float redm[NH][4];
  __shared__ float reds[NH][4];
  int t = threadIdx.x;
  int q = ((blockIdx.x & 7) << 6) + (blockIdx.x >> 3);   // XCD swizzle
  int b = q >> 8, qi = q & (NTOK - 1);
  int j = t;
  int lane = t & 63, w4 = t >> 6;
  const float* srow = S + ((size_t)(b * NH) * NTOK + qi) * NTOK + j;
  float4 d0 = *(const float4*)(Dj + ((size_t)(b * NTOK) + j) * NH);
  float4 d1 = *(const float4*)(Dj + ((size_t)(b * NTOK) + j) * NH + 4);
  float sc[NH];
#pragma unroll
  for (int h = 0; h < NH; ++h) sc[h] = srow[(size_t)h * NTOK * NTOK];
  sc[0] += d0.x; sc[1] += d0.y; sc[2] += d0.z; sc[3] += d0.w;
  sc[4] += d1.x; sc[5] += d1.y; sc[6] += d1.z; sc[7] += d1.w;
#pragma unroll
  for (int h = 0; h < NH; ++h) {
    float m = sc[h];
#pragma unroll
    for (int off = 32; off >= 1; off >>= 1) m = fmaxf(m, __shfl_xor(m, off));
    if (lane == 0) redm[h][w4] = m;
  }
  __syncthreads();
#pragma unroll
  for (int h = 0; h < NH; ++h) {
    float m = fmaxf(fmaxf(redm[h][0], redm[h][1]), fmaxf(redm[h][2], redm[h][3]));
    float e = __expf(sc[h] - m);
    sc[h] = e;
    float s = e;
#pragma unroll
    for (int off = 32; off >= 1; off >>= 1) s += __shfl_xor(s, off);
    if (lane == 0) reds[h][w4] = s;
  }
  __syncthreads();
#pragma unroll
  for (int h = 0; h < NH; ++h) {
    float s = (reds[h][0] + reds[h][1]) + (reds[h][2] + reds[h][3]);
    float w = sc[h] * __builtin_amdgcn_rcpf(s);
    Wsmb[((size_t)(b * NH + h) * NTOK + qi) * WSTR + j] = bf16_rne(w);
  }
}

// ---------------- pv_gemm (MFMA): P1=W@Pv, P2=W@Pv2 -> Taylor epilogue -> Gb --------
// grid (32 = 4 i-tiles x 8 d-tiles, 16 bh), 256 thr, wave = 16i x 64d, dual acc.
__global__ __launch_bounds__(256) void pv_gemm(
    const ushort16* __restrict__ Wsmb, const ushort16* __restrict__ PvT,
    const ushort16* __restrict__ Pv2T, const float* __restrict__ Sv,
    ushort16* __restrict__ Gb) {
  int t = threadIdx.x;
  int w = t >> 6, lane = t & 63;
  int bh = blockIdx.y;
  int b = bh >> 3;
  int ib = (blockIdx.x >> 3) * 64 + w * 16;
  int d0 = (blockIdx.x & 7) * 64;
  f32x4 a1[4] = {}, a2[4] = {};
  const ushort16* abase = Wsmb + ((size_t)bh * NTOK + ib) * WSTR;
  const ushort16* b1 = PvT + ((size_t)(b * DM) + d0) * TSTR;
  const ushort16* b2 = Pv2T + ((size_t)(b * DM) + d0) * TSTR;
#pragma unroll 2
  for (int kb = 0; kb < 8; ++kb) {
    bf16x8 af = ldfrag(abase + kb * 32, WSTR);
#pragma unroll
    for (int dd = 0; dd < 4; ++dd) {
      bf16x8 f1 = ldfrag(b1 + (size_t)dd * 16 * TSTR + kb * 32, TSTR);
      a1[dd] = __builtin_amdgcn_mfma_f32_16x16x32_bf16(af, f1, a1[dd], 0, 0, 0);
      bf16x8 f2 = ldfrag(b2 + (size_t)dd * 16 * TSTR + kb * 32, TSTR);
      a2[dd] = __builtin_amdgcn_mfma_f32_16x16x32_bf16(af, f2, a2[dd], 0, 0, 0);
    }
  }
  int col = lane & 15, rb = (lane >> 4) * 4;
#pragma unroll
  for (int dd = 0; dd < 4; ++dd) {
#pragma unroll
    for (int r = 0; r < 4; ++r) {
      int ig = ib + rb + r;
      int dg = d0 + dd * 16 + col;
      float sv = Sv[((size_t)(b * NTOK) + ig) * DM + dg];
      float p1 = a1[dd][r], p2 = a2[dd][r];
      float g = 0.5f * (sv - p1) + 0.25f * (sv * sv - 2.f * sv * p1 + p2);
      Gb[((size_t)bh * NTOK + ig) * PD + dg] = bf16_rne(g);
    }
  }
}

// ---------------- out_gemm (MFMA): out = Gb@Wv2^T + Wsm@V + bv2 ----------------
// grid (16 i-tiles of 16, 16 bh), 64 thr = 1 wave, 16i x 64o, K = 512 + 256.
__global__ __launch_bounds__(64) void out_gemm(
    const ushort16* __restrict__ Gb, const ushort16* __restrict__ Wv2b,
    const ushort16* __restrict__ Wsmb, const ushort16* __restrict__ VTb,
    const float* __restrict__ bv2, float* __restrict__ out) {
  int lane = threadIdx.x;
  int bh = blockIdx.y;
  int b = bh >> 3, h = bh & 7;
  int ib = blockIdx.x * 16;
  f32x4 acc[4] = {};
  {  // G @ Wv2_h^T, K=512
    const ushort16* abase = Gb + ((size_t)bh * NTOK + ib) * PD;
    const ushort16* bbase = Wv2b + (size_t)(h * HDIM) * PD;
#pragma unroll 4
    for (int kb = 0; kb < 16; ++kb) {
      bf16x8 af = ldfrag(abase + kb * 32, PD);
#pragma unroll
      for (int dd = 0; dd < 4; ++dd) {
        bf16x8 bf = ldfrag(bbase + (size_t)dd * 16 * PD + kb * 32, PD);
        acc[dd] = __builtin_amdgcn_mfma_f32_16x16x32_bf16(af, bf, acc[dd], 0, 0, 0);
      }
    }
  }
  {  // Wsm @ V, K=256
    const ushort16* abase = Wsmb + ((size_t)bh * NTOK + ib) * WSTR;
    const ushort16* bbase = VTb + (size_t)bh * HDIM * TSTR;
#pragma unroll 2
    for (int kb = 0; kb < 8; ++kb) {
      bf16x8 af = ldfrag(abase + kb * 32, WSTR);
#pragma unroll
      for (int dd = 0; dd < 4; ++dd) {
        bf16x8 bf = ldfrag(bbase + (size_t)dd * 16 * TSTR + kb * 32, TSTR);
        acc[dd] = __builtin_amdgcn_mfma_f32_16x16x32_bf16(af, bf, acc[dd], 0, 0, 0);
      }
    }
  }
  int col = lane & 15, rb = (lane >> 4) * 4;
#pragma unroll
  for (int dd = 0; dd < 4; ++dd) {
#pragma unroll
    for (int r = 0; r < 4; ++r) {
      int ig = ib + rb + r;
      int dp = dd * 16 + col;
      out[((size_t)(b * NTOK) + ig) * DM + h * HDIM + dp] = acc[dd][r] + bv2[h * HDIM + dp];
    }
  }
}

extern "C" void kernel_launch(void* const* d_in, const int* in_sizes, int n_in,
                              void* d_out, int out_size, void* d_ws, size_t ws_size,
                              hipStream_t stream) {
  const float* x      = (const float*)d_in[0];
  const float* coords = (const float*)d_in[1];
  const float* Wqkv   = (const float*)d_in[2];
  const float* bqkv   = (const float*)d_in[3];
  const float* Wb1    = (const float*)d_in[4];
  const float* bb1    = (const float*)d_in[5];
  const float* Wb2    = (const float*)d_in[6];
  // d_in[7] = bb2: softmax-invariant, unused
  const float* Wv1    = (const float*)d_in[8];
  const float* bv1    = (const float*)d_in[9];
  const float* Wv2    = (const float*)d_in[10];
  const float* bv2    = (const float*)d_in[11];
  float* outp = (float*)d_out;
  float* ws = (float*)d_ws;

  const size_t SZ = (size_t)BATCH * NTOK * DM;           // 262144
  const size_t SQ = (size_t)BATCH * NH * NTOK * NTOK;    // 1048576
  float* Svw = ws;
  float* Sqk = ws + SZ;
  float* Djw = Sqk + SQ;                                 // 4096 floats
  ushort16* SbW  = (ushort16*)(Djw + 4096);              // [bh][tok][PD]
  ushort16* Pbw  = SbW + (size_t)BATCH * NH * NTOK * PD;
  ushort16* PvT  = Pbw + (size_t)BATCH * NTOK * PD;      // [b][d][TSTR]
  ushort16* Pv2T = PvT + (size_t)BATCH * DM * TSTR;
  ushort16* Wsmb = Pv2T + (size_t)BATCH * DM * TSTR;     // [bh][i][WSTR]
  ushort16* Gb   = Wsmb + (size_t)BATCH * NH * NTOK * WSTR;  // [bh][i][PD]
  ushort16* Qb   = Gb + (size_t)BATCH * NH * NTOK * PD;      // [bh][i][64]
  ushort16* Kb   = Qb + (size_t)BATCH * NH * NTOK * HDIM;
  ushort16* VTb  = Kb + (size_t)BATCH * NH * NTOK * HDIM;    // [bh][dp][TSTR]
  ushort16* Wv2b = VTb + (size_t)BATCH * NH * HDIM * TSTR;   // [o][PD]

  hipLaunchKernelGGL(prep_pe, dim3(BATCH * NTOK), dim3(512), 0, stream,
                     coords, Wb1, bb1, Wv1, bv1, Wb2, Wv2,
                     Svw, SbW, Pbw, PvT, Pv2T, Djw, Wv2b);
  hipLaunchKernelGGL(qkv_gemm, dim3(8, 24), dim3(256), 0, stream,
                     x, Wqkv, bqkv, Qb, Kb, VTb);
  hipLaunchKernelGGL(score_gemm, dim3(16, BATCH * NH), dim3(256), 0, stream,
                     Qb, Kb, SbW, Pbw, Sqk);
  hipLaunchKernelGGL(attn_softmax, dim3(BATCH * NTOK), dim3(256), 0, stream,
                     Sqk, Djw, Wsmb);
  hipLaunchKernelGGL(pv_gemm, dim3(32, BATCH * NH), dim3(256), 0, stream,
                     Wsmb, PvT, Pv2T, Svw, Gb);
  hipLaunchKernelGGL(out_gemm, dim3(16, BATCH * NH), dim3(64), 0, stream,
                     Gb, Wv2b, Wsmb, VTb, bv2, outp);
}

// Round 9
// 77.406 us; speedup vs baseline: 2.1558x; 1.0951x over previous
//
#include <hip/hip_runtime.h>

#define BATCH 2
#define NTOK 256
#define DM 512
#define NH 8
#define HDIM 64
#define PD 520      // bf16 row stride for d-major (k=512) tensors
#define TSTR 264    // bf16 row stride for j-major (k=256) tensors
#define WSTR 264

typedef unsigned int uint32;
typedef unsigned short ushort16;
typedef __attribute__((ext_vector_type(8))) short bf16x8;
typedef __attribute__((ext_vector_type(4))) float f32x4;

static __device__ __forceinline__ ushort16 bf16_rne(float x) {
  uint32 u = __float_as_uint(x);
  u += 0x7fffu + ((u >> 16) & 1u);
  return (ushort16)(u >> 16);
}

// 16x32 bf16 MFMA fragment from row-major [16dim][k]: lane l -> row l&15, k-off (l>>4)*8
static __device__ __forceinline__ bf16x8 ldfrag(const ushort16* p0, int stride) {
  int l = threadIdx.x & 63;
  return *(const bf16x8*)(p0 + (size_t)(l & 15) * stride + ((l >> 4) << 3));
}

// ---------------- prep: per-token tables for the Taylor-factorized pair MLPs ----------
__global__ __launch_bounds__(512) void prep_pe(
    const float* __restrict__ coords,
    const float* __restrict__ Wb1, const float* __restrict__ bb1,
    const float* __restrict__ Wv1, const float* __restrict__ bv1,
    const float* __restrict__ Wb2, const float* __restrict__ Wv2,
    float* __restrict__ Sv, ushort16* __restrict__ SbW,
    ushort16* __restrict__ Pb, ushort16* __restrict__ PvT,
    ushort16* __restrict__ Pv2T, float* __restrict__ DjT,
    ushort16* __restrict__ Wv2b) {
  __shared__ float redD[8][8];
  int q = blockIdx.x;          // b*NTOK + tok
  int b = q >> 8;
  int tok = q & (NTOK - 1);
  int d = threadIdx.x;
  const float* cp = coords + q * 3;
  float c0 = cp[0], c1 = cp[1], c2 = cp[2];
  float pb = Wb1[d * 3 + 0] * c0 + Wb1[d * 3 + 1] * c1 + Wb1[d * 3 + 2] * c2;
  float pv = Wv1[d * 3 + 0] * c0 + Wv1[d * 3 + 1] * c1 + Wv1[d * 3 + 2] * c2;
  float sb = pb + bb1[d];
  float sv = pv + bv1[d];
  Sv[(size_t)q * DM + d] = sv;
  Pb[(size_t)q * PD + d] = bf16_rne(pb);
  PvT [((size_t)(b * DM) + d) * TSTR + tok] = bf16_rne(pv);
  Pv2T[((size_t)(b * DM) + d) * TSTR + tok] = bf16_rne(pv * pv);
  Wv2b[(size_t)q * PD + d] = bf16_rne(Wv2[(size_t)q * DM + d]);  // q spans 512 rows of Wv2
  float w2[NH];
#pragma unroll
  for (int h = 0; h < NH; ++h) w2[h] = Wb2[h * DM + d];
#pragma unroll
  for (int h = 0; h < NH; ++h)
    SbW[((size_t)(b * NH + h) * NTOK + tok) * PD + d] = bf16_rne(-0.5f * w2[h] * sb);
  float u = -0.5f * pb + 0.25f * pb * pb;
  float dp[NH];
#pragma unroll
  for (int h = 0; h < NH; ++h) dp[h] = w2[h] * u;
#pragma unroll
  for (int off = 32; off >= 1; off >>= 1) {
#pragma unroll
    for (int h = 0; h < NH; ++h) dp[h] += __shfl_xor(dp[h], off);
  }
  int lane = d & 63, wid = d >> 6;
  if (lane == 0) {
#pragma unroll
    for (int h = 0; h < NH; ++h) redD[wid][h] = dp[h];
  }
  __syncthreads();
  if (d < NH) {
    float s = 0.f;
#pragma unroll
    for (int w = 0; w < 8; ++w) s += redD[w][d];
    DjT[(size_t)(b * NH + d) * NTOK + tok] = s;   // [bh][j] for coalesced reads
  }
}

// ---------------- QKV projection GEMM (fp32 compute, bf16 outputs) ----------------
__global__ __launch_bounds__(256) void qkv_gemm(
    const float* __restrict__ X, const float* __restrict__ W,
    const float* __restrict__ bqkv,
    ushort16* __restrict__ Qb, ushort16* __restrict__ Kb,
    ushort16* __restrict__ VTb) {
  __shared__ float Xs[64][33];
  __shared__ float Ws[64][33];
  int t = threadIdx.x;
  int bm = blockIdx.x, bn = blockIdx.y;
  int lrow = t >> 2, lk = (t & 3) * 8;
  const float* Xp = X + (bm * 64 + lrow) * DM + lk;
  const float* Wp = W + (bn * 64 + lrow) * DM + lk;
  int tx = t & 15, ty = t >> 4;
  float acc[4][4] = {};
  for (int k0 = 0; k0 < DM; k0 += 32) {
    float4 xa = *(const float4*)(Xp + k0);
    float4 xb = *(const float4*)(Xp + k0 + 4);
    float4 wa = *(const float4*)(Wp + k0);
    float4 wb = *(const float4*)(Wp + k0 + 4);
    __syncthreads();
    Xs[lrow][lk + 0] = xa.x; Xs[lrow][lk + 1] = xa.y;
    Xs[lrow][lk + 2] = xa.z; Xs[lrow][lk + 3] = xa.w;
    Xs[lrow][lk + 4] = xb.x; Xs[lrow][lk + 5] = xb.y;
    Xs[lrow][lk + 6] = xb.z; Xs[lrow][lk + 7] = xb.w;
    Ws[lrow][lk + 0] = wa.x; Ws[lrow][lk + 1] = wa.y;
    Ws[lrow][lk + 2] = wa.z; Ws[lrow][lk + 3] = wa.w;
    Ws[lrow][lk + 4] = wb.x; Ws[lrow][lk + 5] = wb.y;
    Ws[lrow][lk + 6] = wb.z; Ws[lrow][lk + 7] = wb.w;
    __syncthreads();
#pragma unroll
    for (int kk = 0; kk < 32; ++kk) {
      float a0 = Xs[ty * 4 + 0][kk], a1 = Xs[ty * 4 + 1][kk];
      float a2 = Xs[ty * 4 + 2][kk], a3 = Xs[ty * 4 + 3][kk];
      float b0 = Ws[tx * 4 + 0][kk], b1 = Ws[tx * 4 + 1][kk];
      float b2 = Ws[tx * 4 + 2][kk], b3 = Ws[tx * 4 + 3][kk];
      acc[0][0] = fmaf(a0, b0, acc[0][0]); acc[0][1] = fmaf(a0, b1, acc[0][1]);
      acc[0][2] = fmaf(a0, b2, acc[0][2]); acc[0][3] = fmaf(a0, b3, acc[0][3]);
      acc[1][0] = fmaf(a1, b0, acc[1][0]); acc[1][1] = fmaf(a1, b1, acc[1][1]);
      acc[1][2] = fmaf(a1, b2, acc[1][2]); acc[1][3] = fmaf(a1, b3, acc[1][3]);
      acc[2][0] = fmaf(a2, b0, acc[2][0]); acc[2][1] = fmaf(a2, b1, acc[2][1]);
      acc[2][2] = fmaf(a2, b2, acc[2][2]); acc[2][3] = fmaf(a2, b3, acc[2][3]);
      acc[3][0] = fmaf(a3, b0, acc[3][0]); acc[3][1] = fmaf(a3, b1, acc[3][1]);
      acc[3][2] = fmaf(a3, b2, acc[3][2]); acc[3][3] = fmaf(a3, b3, acc[3][3]);
    }
  }
#pragma unroll
  for (int r = 0; r < 4; ++r) {
    int row = bm * 64 + ty * 4 + r;
    int b = row >> 8, i = row & (NTOK - 1);
#pragma unroll
    for (int c = 0; c < 4; ++c) {
      int n = bn * 64 + tx * 4 + c;
      float val = acc[r][c] + bqkv[n];
      if (n < DM) {
        int h = n >> 6, dp = n & 63;
        Qb[((size_t)(b * NH + h) * NTOK + i) * HDIM + dp] = bf16_rne(val * 0.125f);
      } else if (n < 2 * DM) {
        int u = n - DM; int h = u >> 6, dp = u & 63;
        Kb[((size_t)(b * NH + h) * NTOK + i) * HDIM + dp] = bf16_rne(val);
      } else {
        int u = n - 2 * DM; int h = u >> 6, dp = u & 63;
        VTb[((size_t)(b * NH + h) * HDIM + dp) * TSTR + i] = bf16_rne(val);
      }
    }
  }
}

// ---------------- score_softmax (MFMA + fused softmax) ----------------
// grid (16 i-tiles, 16 bh), 256 thr = 4 waves. Wave w: full 16i x 64j strip (j0=w*64),
// K = 64 (qk) + 512 (C-term). Softmax: in-wave 16-lane shfl partials + LDS combine.
__global__ __launch_bounds__(256) void score_softmax(
    const ushort16* __restrict__ Qb, const ushort16* __restrict__ Kb,
    const ushort16* __restrict__ SbW, const ushort16* __restrict__ Pb,
    const float* __restrict__ DjT, ushort16* __restrict__ Wsmb) {
  __shared__ float redm[4][16];
  __shared__ float reds[4][16];
  int t = threadIdx.x;
  int w = t >> 6, lane = t & 63;
  int bh = blockIdx.y;
  int b = bh >> 3;
  int ib = blockIdx.x * 16;
  int j0 = w * 64;
  int col = lane & 15, rb = (lane >> 4) * 4;
  f32x4 acc[4] = {};
  {  // qk over K=64
    const ushort16* qbase = Qb + ((size_t)bh * NTOK + ib) * HDIM;
    const ushort16* kbase = Kb + ((size_t)bh * NTOK + j0) * HDIM;
#pragma unroll
    for (int kb = 0; kb < 2; ++kb) {
      bf16x8 af = ldfrag(qbase + kb * 32, HDIM);
#pragma unroll
      for (int jf = 0; jf < 4; ++jf) {
        bf16x8 bf = ldfrag(kbase + (size_t)jf * 16 * HDIM + kb * 32, HDIM);
        acc[jf] = __builtin_amdgcn_mfma_f32_16x16x32_bf16(af, bf, acc[jf], 0, 0, 0);
      }
    }
  }
  {  // C-term over K=512 (-0.5 folded into SbW)
    const ushort16* abase = SbW + ((size_t)bh * NTOK + ib) * PD;
    const ushort16* bbase = Pb + ((size_t)(b * NTOK) + j0) * PD;
#pragma unroll 4
    for (int kb = 0; kb < 16; ++kb) {
      bf16x8 af = ldfrag(abase + kb * 32, PD);
#pragma unroll
      for (int jf = 0; jf < 4; ++jf) {
        bf16x8 bf = ldfrag(bbase + (size_t)jf * 16 * PD + kb * 32, PD);
        acc[jf] = __builtin_amdgcn_mfma_f32_16x16x32_bf16(af, bf, acc[jf], 0, 0, 0);
      }
    }
  }
  // scores = acc + Dj (j-only key-side Taylor bias); rows = ib+rb+r, cols j0+jf*16+col
  float sc[4][4];
#pragma unroll
  for (int jf = 0; jf < 4; ++jf) {
    float dj = DjT[(size_t)bh * NTOK + j0 + jf * 16 + col];
#pragma unroll
    for (int r = 0; r < 4; ++r) sc[jf][r] = acc[jf][r] + dj;
  }
  // per-row max within wave's 64 j (16-lane groups share rows)
#pragma unroll
  for (int r = 0; r < 4; ++r) {
    float m = fmaxf(fmaxf(sc[0][r], sc[1][r]), fmaxf(sc[2][r], sc[3][r]));
    m = fmaxf(m, __shfl_xor(m, 1));
    m = fmaxf(m, __shfl_xor(m, 2));
    m = fmaxf(m, __shfl_xor(m, 4));
    m = fmaxf(m, __shfl_xor(m, 8));
    if (col == 0) redm[w][rb + r] = m;
  }
  __syncthreads();
  float mrow[4];
#pragma unroll
  for (int r = 0; r < 4; ++r)
    mrow[r] = fmaxf(fmaxf(redm[0][rb + r], redm[1][rb + r]),
                    fmaxf(redm[2][rb + r], redm[3][rb + r]));
#pragma unroll
  for (int r = 0; r < 4; ++r) {
    float su = 0.f;
#pragma unroll
    for (int jf = 0; jf < 4; ++jf) {
      float e = __expf(sc[jf][r] - mrow[r]);
      sc[jf][r] = e;
      su += e;
    }
    su += __shfl_xor(su, 1);
    su += __shfl_xor(su, 2);
    su += __shfl_xor(su, 4);
    su += __shfl_xor(su, 8);
    if (col == 0) reds[w][rb + r] = su;
  }
  __syncthreads();
#pragma unroll
  for (int r = 0; r < 4; ++r) {
    float stot = (reds[0][rb + r] + reds[1][rb + r]) + (reds[2][rb + r] + reds[3][rb + r]);
    float inv = __builtin_amdgcn_rcpf(stot);
    int row = ib + rb + r;
#pragma unroll
    for (int jf = 0; jf < 4; ++jf)
      Wsmb[((size_t)bh * NTOK + row) * WSTR + j0 + jf * 16 + col] = bf16_rne(sc[jf][r] * inv);
  }
}

// ---------------- pv_out (MFMA): P1/P2 GEMMs -> Taylor g (LDS) -> out GEMM ----------
// grid (16 i-tiles, 16 bh), 256 thr = 4 waves.
// Phase A: wave w computes P1,P2 for 16i x 128d (d0=w*128), K=256; g -> LDS bf16.
// Phase B: wave w computes out 16i x 16o (o0=w*16): g@Wv2^T (K=512, A from LDS)
//          + Wsm@V (K=256), + bv2.
__global__ __launch_bounds__(256) void pv_out(
    const ushort16* __restrict__ Wsmb, const ushort16* __restrict__ PvT,
    const ushort16* __restrict__ Pv2T, const float* __restrict__ Sv,
    const ushort16* __restrict__ Wv2b, const ushort16* __restrict__ VTb,
    const float* __restrict__ bv2, float* __restrict__ out) {
  __shared__ ushort16 gsh[16][DM + 8];   // 16 x 520 bf16 = 16.6 KB
  int t = threadIdx.x;
  int w = t >> 6, lane = t & 63;
  int bh = blockIdx.y;
  int b = bh >> 3, h = bh & 7;
  int ib = blockIdx.x * 16;
  int col = lane & 15, rb = (lane >> 4) * 4;
  int d0 = w * 128;
  const ushort16* abase = Wsmb + ((size_t)bh * NTOK + ib) * WSTR;
  f32x4 a1[8] = {}, a2[8] = {};
  {
    const ushort16* b1 = PvT + ((size_t)(b * DM) + d0) * TSTR;
    const ushort16* b2 = Pv2T + ((size_t)(b * DM) + d0) * TSTR;
#pragma unroll 2
    for (int kb = 0; kb < 8; ++kb) {
      bf16x8 af = ldfrag(abase + kb * 32, WSTR);
#pragma unroll
      for (int df = 0; df < 8; ++df) {
        bf16x8 f1 = ldfrag(b1 + (size_t)df * 16 * TSTR + kb * 32, TSTR);
        a1[df] = __builtin_amdgcn_mfma_f32_16x16x32_bf16(af, f1, a1[df], 0, 0, 0);
        bf16x8 f2 = ldfrag(b2 + (size_t)df * 16 * TSTR + kb * 32, TSTR);
        a2[df] = __builtin_amdgcn_mfma_f32_16x16x32_bf16(af, f2, a2[df], 0, 0, 0);
      }
    }
  }
  // Taylor epilogue -> g (bf16) into LDS
#pragma unroll
  for (int df = 0; df < 8; ++df) {
#pragma unroll
    for (int r = 0; r < 4; ++r) {
      int ig = ib + rb + r;
      int dg = d0 + df * 16 + col;
      float sv = Sv[((size_t)(b * NTOK) + ig) * DM + dg];
      float p1 = a1[df][r], p2 = a2[df][r];
      float g = 0.5f * (sv - p1) + 0.25f * (sv * sv - 2.f * sv * p1 + p2);
      gsh[rb + r][dg] = bf16_rne(g);
    }
  }
  __syncthreads();
  // Phase B: out strip o0 = w*16
  f32x4 acc = {};
  {  // g @ Wv2_h^T, K=512, A from LDS
    const ushort16* wvb = Wv2b + (size_t)(h * HDIM + w * 16) * PD;
#pragma unroll 4
    for (int kb = 0; kb < 16; ++kb) {
      bf16x8 af = *(const bf16x8*)&gsh[col][kb * 32 + ((lane >> 4) << 3)];
      bf16x8 bf = ldfrag(wvb + kb * 32, PD);
      acc = __builtin_amdgcn_mfma_f32_16x16x32_bf16(af, bf, acc, 0, 0, 0);
    }
  }
  {  // Wsm @ V, K=256
    const ushort16* vtb = VTb + (size_t)(bh * HDIM + w * 16) * TSTR;
#pragma unroll 2
    for (int kb = 0; kb < 8; ++kb) {
      bf16x8 af = ldfrag(abase + kb * 32, WSTR);
      bf16x8 bf = ldfrag(vtb + kb * 32, TSTR);
      acc = __builtin_amdgcn_mfma_f32_16x16x32_bf16(af, bf, acc, 0, 0, 0);
    }
  }
#pragma unroll
  for (int r = 0; r < 4; ++r) {
    int ig = ib + rb + r;
    int o = h * HDIM + w * 16 + col;
    out[((size_t)(b * NTOK) + ig) * DM + o] = acc[r] + bv2[o];
  }
}

extern "C" void kernel_launch(void* const* d_in, const int* in_sizes, int n_in,
                              void* d_out, int out_size, void* d_ws, size_t ws_size,
                              hipStream_t stream) {
  const float* x      = (const float*)d_in[0];
  const float* coords = (const float*)d_in[1];
  const float* Wqkv   = (const float*)d_in[2];
  const float* bqkv   = (const float*)d_in[3];
  const float* Wb1    = (const float*)d_in[4];
  const float* bb1    = (const float*)d_in[5];
  const float* Wb2    = (const float*)d_in[6];
  // d_in[7] = bb2: softmax-invariant, unused
  const float* Wv1    = (const float*)d_in[8];
  const float* bv1    = (const float*)d_in[9];
  const float* Wv2    = (const float*)d_in[10];
  const float* bv2    = (const float*)d_in[11];
  float* outp = (float*)d_out;
  float* ws = (float*)d_ws;

  const size_t SZ = (size_t)BATCH * NTOK * DM;           // 262144
  float* Svw = ws;
  float* DjT = ws + SZ;                                  // [bh][j], 4096 floats
  ushort16* SbW  = (ushort16*)(DjT + 4096);              // [bh][tok][PD]
  ushort16* Pbw  = SbW + (size_t)BATCH * NH * NTOK * PD;
  ushort16* PvT  = Pbw + (size_t)BATCH * NTOK * PD;      // [b][d][TSTR]
  ushort16* Pv2T = PvT + (size_t)BATCH * DM * TSTR;
  ushort16* Wsmb = Pv2T + (size_t)BATCH * DM * TSTR;     // [bh][i][WSTR]
  ushort16* Qb   = Wsmb + (size_t)BATCH * NH * NTOK * WSTR;  // [bh][i][64]
  ushort16* Kb   = Qb + (size_t)BATCH * NH * NTOK * HDIM;
  ushort16* VTb  = Kb + (size_t)BATCH * NH * NTOK * HDIM;    // [bh][dp][TSTR]
  ushort16* Wv2b = VTb + (size_t)BATCH * NH * HDIM * TSTR;   // [o][PD]

  hipLaunchKernelGGL(prep_pe, dim3(BATCH * NTOK), dim3(512), 0, stream,
                     coords, Wb1, bb1, Wv1, bv1, Wb2, Wv2,
                     Svw, SbW, Pbw, PvT, Pv2T, DjT, Wv2b);
  hipLaunchKernelGGL(qkv_gemm, dim3(8, 24), dim3(256), 0, stream,
                     x, Wqkv, bqkv, Qb, Kb, VTb);
  hipLaunchKernelGGL(score_softmax, dim3(16, BATCH * NH), dim3(256), 0, stream,
                     Qb, Kb, SbW, Pbw, DjT, Wsmb);
  hipLaunchKernelGGL(pv_out, dim3(16, BATCH * NH), dim3(256), 0, stream,
                     Wsmb, PvT, Pv2T, Svw, Wv2b, VTb, bv2, outp);
}